// Round 8
// baseline (713.660 us; speedup 1.0000x reference)
//
#include <hip/hip_runtime.h>

// GConvGRU (ChebConv K=3, GRU with H=0) on MI355X.
// H=0 => out = (1 - sigmoid(Cz + bhz)) * tanh(Ch + bhh); Cz/Ch share the
// Chebyshev basis Tx0=x, Tx1=P x, Tx2=2 P Tx1 - x, P = -D^{-1/2} A D^{-1/2}.
// Factorization: P v = -dinv .* (A_w^T (dinv .* v)), so records store raw w.
//
// Round-7 counters: propacc gather-latency bound (178us, 1.2 TB/s, VALU 3.4%,
// occ 82%: ONE outstanding y[src] gather per wave, partially HBM-missing).
// Fix: 8-wide batched loads/gathers per thread (8 outstanding gathers/wave).

static constexpr int BLK = 256;
static constexpr int BLK_SS = 512;      // sortscatter block
static constexpr int BLK_ACC = 512;
static constexpr int NBC_MAX = 512;     // max coarse buckets (n <= 2^19)
static constexpr int BSHIFT = 10;       // 1024 nodes/bucket
static constexpr int BSIZE = 1024;
static constexpr int SCH = 4096;        // edges per sort-scatter chunk

__device__ __forceinline__ void atomAddF(float* p, float v) {
    unsafeAtomicAdd(p, v);
}

// ---------------- utility ----------------

__global__ void k_zero_ints(int* __restrict__ p, int n)
{
    int i = blockIdx.x * blockDim.x + threadIdx.x;
    if (i < n) p[i] = 0;
}

__global__ void k_zero_f4(float4* __restrict__ p, long long n4)
{
    long long i = (long long)blockIdx.x * blockDim.x + threadIdx.x;
    long long stride = (long long)gridDim.x * blockDim.x;
    for (; i < n4; i += stride) p[i] = make_float4(0.f, 0.f, 0.f, 0.f);
}

// ---------------- histogram + scan ----------------

__global__ void k_hist(const int* __restrict__ srcp, const int* __restrict__ dstp,
                       int* __restrict__ histS, int* __restrict__ histD,
                       long long ne, int NB)
{
    __shared__ int lS[NBC_MAX];
    __shared__ int lD[NBC_MAX];
    for (int b = threadIdx.x; b < NB; b += blockDim.x) { lS[b] = 0; lD[b] = 0; }
    __syncthreads();

    const long long ng = (ne + 3) >> 2;
    const long long stride = (long long)gridDim.x * blockDim.x;
    for (long long g = (long long)blockIdx.x * blockDim.x + threadIdx.x; g < ng; g += stride) {
        const long long e = g << 2;
        if (e + 3 < ne) {
            int4 s4 = *(const int4*)(srcp + e);
            int4 d4 = *(const int4*)(dstp + e);
            atomicAdd(&lS[s4.x >> BSHIFT], 1); atomicAdd(&lS[s4.y >> BSHIFT], 1);
            atomicAdd(&lS[s4.z >> BSHIFT], 1); atomicAdd(&lS[s4.w >> BSHIFT], 1);
            atomicAdd(&lD[d4.x >> BSHIFT], 1); atomicAdd(&lD[d4.y >> BSHIFT], 1);
            atomicAdd(&lD[d4.z >> BSHIFT], 1); atomicAdd(&lD[d4.w >> BSHIFT], 1);
        } else {
            for (long long q = e; q < ne; ++q) {
                atomicAdd(&lS[srcp[q] >> BSHIFT], 1);
                atomicAdd(&lD[dstp[q] >> BSHIFT], 1);
            }
        }
    }
    __syncthreads();
    for (int b = threadIdx.x; b < NB; b += blockDim.x) {
        if (lS[b]) atomicAdd(&histS[b], lS[b]);
        if (lD[b]) atomicAdd(&histD[b], lD[b]);
    }
}

// Exclusive scan: block 0 does S, block 1 does D. NB <= 512, BLK=256.
__global__ void k_scan(const int* __restrict__ histS, int* __restrict__ baseS, int* __restrict__ curS,
                       const int* __restrict__ histD, int* __restrict__ baseD, int* __restrict__ curD,
                       int NB)
{
    const int* hist = (blockIdx.x == 0) ? histS : histD;
    int* base = (blockIdx.x == 0) ? baseS : baseD;
    int* cur  = (blockIdx.x == 0) ? curS  : curD;

    __shared__ int part[BLK];
    int t = threadIdx.x;
    int v0 = (2 * t     < NB) ? hist[2 * t]     : 0;
    int v1 = (2 * t + 1 < NB) ? hist[2 * t + 1] : 0;
    part[t] = v0 + v1;
    __syncthreads();
    for (int off = 1; off < BLK; off <<= 1) {
        int val = (t >= off) ? part[t - off] : 0;
        __syncthreads();
        part[t] += val;
        __syncthreads();
    }
    int run = (t == 0) ? 0 : part[t - 1];
    if (2 * t < NB)     { base[2 * t] = run;          cur[2 * t] = run; }
    if (2 * t + 1 < NB) { base[2 * t + 1] = run + v0; cur[2 * t + 1] = run + v0; }
}

// ---------------- LDS-sorted scatter ----------------
// phase 0 (MODE&1): src-partition -> recS (4B): (w & 0xFFFFFC00) | srcLocal
// phase 1 (MODE&2): dst-partition -> recD (8B): { src | dstLocal<<19, w }
// Each block sorts its SCH-edge chunk in LDS, then flushes bucket-contiguous.
// Chunk order is XCD-swizzled (bijective) so adjacent appends share an L2.
template <int MODE>
__global__ __launch_bounds__(BLK_SS)
void k_sortscatter(const int* __restrict__ srcp, const int* __restrict__ dstp,
                   const float* __restrict__ w,
                   int* __restrict__ curS, int* __restrict__ curD,
                   unsigned* __restrict__ recS, uint2* __restrict__ recD,
                   long long ne, int NB, int NCH)
{
    __shared__ uint2 stage[SCH];            // 32 KB (phase1); phase0 aliases 16 KB
    __shared__ unsigned short slotbkt[SCH]; // 8 KB
    __shared__ int loff[NBC_MAX];           // excl offsets -> atomic cursors
    __shared__ int gdelta[NBC_MAX];
    __shared__ int stmp[BLK_SS];
    unsigned* stage0 = (unsigned*)stage;

    const int orig = blockIdx.x;
    const int xcd = orig & 7, idx = orig >> 3;
    const int q8 = NCH >> 3, r8 = NCH & 7;
    const int chunk = (xcd < r8 ? xcd * (q8 + 1) : r8 * (q8 + 1) + (xcd - r8) * q8) + idx;

    const long long cs = (long long)chunk * SCH;
    if (cs >= ne) return;
    const int cnt_chunk = (int)(((cs + SCH) < ne) ? SCH : (ne - cs));
    const int t = threadIdx.x;

    for (int phase = 0; phase < 2; ++phase) {
        if (!(MODE & (1 << phase))) continue;
        const int* keys = phase ? dstp : srcp;
        int* cur = phase ? curD : curS;

        for (int b = t; b < NB; b += BLK_SS) loff[b] = 0;
        __syncthreads();

        // pass 1: count
        for (int i = t * 4; i < cnt_chunk; i += BLK_SS * 4) {
            if (i + 3 < cnt_chunk) {
                int4 k4 = *(const int4*)(keys + cs + i);
                atomicAdd(&loff[k4.x >> BSHIFT], 1); atomicAdd(&loff[k4.y >> BSHIFT], 1);
                atomicAdd(&loff[k4.z >> BSHIFT], 1); atomicAdd(&loff[k4.w >> BSHIFT], 1);
            } else {
                for (int q = i; q < cnt_chunk; ++q)
                    atomicAdd(&loff[keys[cs + q] >> BSHIFT], 1);
            }
        }
        __syncthreads();

        // scan counts (1 bucket/thread) -> excl offsets; reserve global space
        int v = (t < NB) ? loff[t] : 0;
        stmp[t] = v;
        __syncthreads();
        for (int off = 1; off < BLK_SS; off <<= 1) {
            int val = (t >= off) ? stmp[t - off] : 0;
            __syncthreads();
            stmp[t] += val;
            __syncthreads();
        }
        int excl = stmp[t] - v;
        if (t < NB) {
            int g = (v > 0) ? atomicAdd(&cur[t], v) : 0;
            loff[t] = excl;          // becomes the place cursor
            gdelta[t] = g - excl;
        }
        __syncthreads();

        // pass 2: place records bucket-sorted (loff is the cursor)
        for (int i = t * 4; i < cnt_chunk; i += BLK_SS * 4) {
            if (i + 3 < cnt_chunk) {
                int4 s4 = *(const int4*)(srcp + cs + i);
                int4 d4 = *(const int4*)(dstp + cs + i);
                float4 w4 = *(const float4*)(w + cs + i);
                int ss[4] = {s4.x, s4.y, s4.z, s4.w};
                int dd[4] = {d4.x, d4.y, d4.z, d4.w};
                float wv[4] = {w4.x, w4.y, w4.z, w4.w};
#pragma unroll
                for (int j = 0; j < 4; ++j) {
                    float we = (ss[j] == dd[j]) ? 0.0f : wv[j];
                    int key = phase ? dd[j] : ss[j];
                    int b = key >> BSHIFT;
                    int pos = atomicAdd(&loff[b], 1);
                    if (phase) {
                        stage[pos] = make_uint2(
                            (unsigned)ss[j] | ((unsigned)(dd[j] & (BSIZE - 1)) << 19),
                            __float_as_uint(we));
                    } else {
                        stage0[pos] = (__float_as_uint(we) & 0xFFFFFC00u)
                                    | (unsigned)(ss[j] & (BSIZE - 1));
                    }
                    slotbkt[pos] = (unsigned short)b;
                }
            } else {
                for (int q = i; q < cnt_chunk; ++q) {
                    int s = srcp[cs + q], d = dstp[cs + q];
                    float we = (s == d) ? 0.0f : w[cs + q];
                    int key = phase ? d : s;
                    int b = key >> BSHIFT;
                    int pos = atomicAdd(&loff[b], 1);
                    if (phase) {
                        stage[pos] = make_uint2(
                            (unsigned)s | ((unsigned)(d & (BSIZE - 1)) << 19),
                            __float_as_uint(we));
                    } else {
                        stage0[pos] = (__float_as_uint(we) & 0xFFFFFC00u)
                                    | (unsigned)(s & (BSIZE - 1));
                    }
                    slotbkt[pos] = (unsigned short)b;
                }
            }
        }
        __syncthreads();

        // pass 3: flush (runs are time- and address-contiguous)
        for (int i = t; i < cnt_chunk; i += BLK_SS) {
            int b = slotbkt[i];
            if (phase) recD[(long long)(i + gdelta[b])] = stage[i];
            else       recS[(long long)(i + gdelta[b])] = stage0[i];
        }
        __syncthreads();
    }
}

// ---------------- split accumulate + combine ----------------

// deg partial from 4B records (4-wide batched stream).
__global__ __launch_bounds__(BLK_ACC)
void k_degacc(const unsigned* __restrict__ recs, const int* __restrict__ base,
              const int* __restrict__ hist, float* __restrict__ part, int split)
{
    __shared__ float lacc[BSIZE];
    const int b = blockIdx.x / split, sp = blockIdx.x % split;
    for (int i = threadIdx.x; i < BSIZE; i += blockDim.x) lacc[i] = 0.0f;
    __syncthreads();
    const int cnt = hist[b];
    const unsigned* rp = recs + base[b];
    const int i0 = (int)((long long)cnt * sp / split);
    const int i1 = (int)((long long)cnt * (sp + 1) / split);
    int r = i0 + threadIdx.x;
    for (; r + 3 * BLK_ACC < i1; r += 4 * BLK_ACC) {
        unsigned rc[4];
#pragma unroll
        for (int u = 0; u < 4; ++u) rc[u] = rp[r + u * BLK_ACC];
#pragma unroll
        for (int u = 0; u < 4; ++u)
            atomicAdd(&lacc[rc[u] & (BSIZE - 1u)], __uint_as_float(rc[u] & 0xFFFFFC00u));
    }
    for (; r < i1; r += BLK_ACC) {
        unsigned rc = rp[r];
        atomicAdd(&lacc[rc & (BSIZE - 1u)], __uint_as_float(rc & 0xFFFFFC00u));
    }
    __syncthreads();
    float* dst = part + (size_t)(b * split + sp) * BSIZE;
    for (int i = threadIdx.x; i < BSIZE; i += blockDim.x) dst[i] = lacc[i];
}

// combine deg partials -> dinv, y0 = dinv*x
__global__ void k_degfin(const float* __restrict__ part, const float2* __restrict__ x,
                         float* __restrict__ dinv, float2* __restrict__ y0,
                         int n, int split)
{
    int node = blockIdx.x * blockDim.x + threadIdx.x;
    if (node >= n) return;
    int b = node >> BSHIFT, loc = node & (BSIZE - 1);
    float dg = 0.0f;
    for (int sp = 0; sp < split; ++sp)
        dg += part[(size_t)(b * split + sp) * BSIZE + loc];
    float di = (dg > 0.0f) ? rsqrtf(dg) : 0.0f;
    dinv[node] = di;
    float2 xv = x[node];
    y0[node] = make_float2(di * xv.x, di * xv.y);
}

// prop partial: 8-wide batched record loads + y gathers (8 outstanding/wave).
__global__ __launch_bounds__(BLK_ACC)
void k_propacc(const uint2* __restrict__ recs, const int* __restrict__ base,
               const int* __restrict__ hist, const float2* __restrict__ yin,
               float2* __restrict__ part, int split)
{
    __shared__ float lax[BSIZE];
    __shared__ float lay[BSIZE];
    const int b = blockIdx.x / split, sp = blockIdx.x % split;
    for (int i = threadIdx.x; i < BSIZE; i += blockDim.x) { lax[i] = 0.0f; lay[i] = 0.0f; }
    __syncthreads();
    const int cnt = hist[b];
    const uint2* rp = recs + base[b];
    const int i0 = (int)((long long)cnt * sp / split);
    const int i1 = (int)((long long)cnt * (sp + 1) / split);
    int r = i0 + threadIdx.x;
    for (; r + 7 * BLK_ACC < i1; r += 8 * BLK_ACC) {
        uint2 rc[8];
        float2 yv[8];
#pragma unroll
        for (int u = 0; u < 8; ++u) rc[u] = rp[r + u * BLK_ACC];
#pragma unroll
        for (int u = 0; u < 8; ++u) yv[u] = yin[rc[u].x & 0x7FFFFu];
#pragma unroll
        for (int u = 0; u < 8; ++u) {
            int dl = (int)(rc[u].x >> 19);
            float wv = __uint_as_float(rc[u].y);
            atomicAdd(&lax[dl], wv * yv[u].x);
            atomicAdd(&lay[dl], wv * yv[u].y);
        }
    }
    for (; r < i1; r += BLK_ACC) {
        uint2 rc = rp[r];
        float2 yv = yin[rc.x & 0x7FFFFu];
        int dl = (int)(rc.x >> 19);
        float wv = __uint_as_float(rc.y);
        atomicAdd(&lax[dl], wv * yv.x);
        atomicAdd(&lay[dl], wv * yv.y);
    }
    __syncthreads();
    float2* dst = part + (size_t)(b * split + sp) * BSIZE;
    for (int i = threadIdx.x; i < BSIZE; i += blockDim.x)
        dst[i] = make_float2(lax[i], lay[i]);
}

// combine prop1 partials -> tx1 = -dinv*sum, y1 = dinv*tx1
__global__ void k_propfin1(const float2* __restrict__ part, const float* __restrict__ dinv,
                           float2* __restrict__ tx1, float2* __restrict__ y1,
                           int n, int split)
{
    int node = blockIdx.x * blockDim.x + threadIdx.x;
    if (node >= n) return;
    int b = node >> BSHIFT, loc = node & (BSIZE - 1);
    float sx = 0.0f, sy = 0.0f;
    for (int sp = 0; sp < split; ++sp) {
        float2 v = part[(size_t)(b * split + sp) * BSIZE + loc];
        sx += v.x; sy += v.y;
    }
    float di = dinv[node];
    float ox = -di * sx, oy = -di * sy;
    tx1[node] = make_float2(ox, oy);
    y1[node] = make_float2(di * ox, di * oy);
}

// combine prop2 partials + fused gates -> out
__global__ void k_propfin2(const float2* __restrict__ part, const float* __restrict__ dinv,
                           const float2* __restrict__ x, const float2* __restrict__ tx1,
                           const float* __restrict__ Wxz, const float* __restrict__ Wxh,
                           const float* __restrict__ bxz, const float* __restrict__ bhz,
                           const float* __restrict__ bxh, const float* __restrict__ bhh,
                           float* __restrict__ out, int n, int split)
{
    int node = blockIdx.x * blockDim.x + threadIdx.x;
    if (node >= n) return;
    int b = node >> BSHIFT, loc = node & (BSIZE - 1);
    float sx = 0.0f, sy = 0.0f;
    for (int sp = 0; sp < split; ++sp) {
        float2 v = part[(size_t)(b * split + sp) * BSIZE + loc];
        sx += v.x; sy += v.y;
    }
    float di = dinv[node];
    float2 t0 = x[node];
    float2 t1 = tx1[node];
    float t2x = 2.0f * (-di * sx) - t0.x;
    float t2y = 2.0f * (-di * sy) - t0.y;
    float z = t0.x * Wxz[0] + t0.y * Wxz[1]
            + t1.x * Wxz[2] + t1.y * Wxz[3]
            + t2x  * Wxz[4] + t2y  * Wxz[5] + bxz[0] + bhz[0];
    float h = t0.x * Wxh[0] + t0.y * Wxh[1]
            + t1.x * Wxh[2] + t1.y * Wxh[3]
            + t2x  * Wxh[4] + t2y  * Wxh[5] + bxh[0] + bhh[0];
    float zs = 1.0f / (1.0f + expf(-z));
    float ht = tanhf(h);
    out[node] = (1.0f - zs) * ht;
}

// ---------------- atomic fallback ----------------

__global__ void k_deg_atomic(const int* __restrict__ srcp, const int* __restrict__ dstp,
                             const float* __restrict__ w, float* __restrict__ deg,
                             long long ne)
{
    const long long ng = (ne + 3) >> 2;
    const long long stride = (long long)gridDim.x * blockDim.x;
    for (long long g = (long long)blockIdx.x * blockDim.x + threadIdx.x; g < ng; g += stride) {
        const long long e = g << 2;
        if (e + 3 < ne) {
            int4 s4 = *(const int4*)(srcp + e);
            int4 d4 = *(const int4*)(dstp + e);
            float4 w4 = *(const float4*)(w + e);
            if (s4.x != d4.x) atomAddF(&deg[s4.x], w4.x);
            if (s4.y != d4.y) atomAddF(&deg[s4.y], w4.y);
            if (s4.z != d4.z) atomAddF(&deg[s4.z], w4.z);
            if (s4.w != d4.w) atomAddF(&deg[s4.w], w4.w);
        } else {
            for (long long q = e; q < ne; ++q) {
                int s = srcp[q], d = dstp[q];
                if (s != d) atomAddF(&deg[s], w[q]);
            }
        }
    }
}

__global__ void k_dinv_inplace(float* __restrict__ deg, int n)
{
    int i = blockIdx.x * blockDim.x + threadIdx.x;
    if (i < n) {
        float d = deg[i];
        deg[i] = (d > 0.0f) ? rsqrtf(d) : 0.0f;
    }
}

__global__ void k_prop_atomic(const int* __restrict__ srcp, const int* __restrict__ dstp,
                              const float* __restrict__ w, const float* __restrict__ dinv,
                              const float2* __restrict__ xin, float* __restrict__ acc,
                              long long ne)
{
    const long long ng = (ne + 3) >> 2;
    const long long stride = (long long)gridDim.x * blockDim.x;
    for (long long g = (long long)blockIdx.x * blockDim.x + threadIdx.x; g < ng; g += stride) {
        const long long e = g << 2;
        if (e + 3 < ne) {
            int4 s4 = *(const int4*)(srcp + e);
            int4 d4 = *(const int4*)(dstp + e);
            float4 w4 = *(const float4*)(w + e);
            int s[4] = {s4.x, s4.y, s4.z, s4.w};
            int d[4] = {d4.x, d4.y, d4.z, d4.w};
            float wv[4] = {w4.x, w4.y, w4.z, w4.w};
#pragma unroll
            for (int j = 0; j < 4; ++j) {
                float wn = (s[j] != d[j]) ? -(dinv[s[j]] * wv[j] * dinv[d[j]]) : 0.0f;
                float2 xv = xin[s[j]];
                atomAddF(&acc[2 * d[j] + 0], wn * xv.x);
                atomAddF(&acc[2 * d[j] + 1], wn * xv.y);
            }
        } else {
            for (long long q = e; q < ne; ++q) {
                int ss = srcp[q], dd = dstp[q];
                float wn = (ss != dd) ? -(dinv[ss] * w[q] * dinv[dd]) : 0.0f;
                float2 xv = xin[ss];
                atomAddF(&acc[2 * dd + 0], wn * xv.x);
                atomAddF(&acc[2 * dd + 1], wn * xv.y);
            }
        }
    }
}

__global__ void k_final(const float2* __restrict__ x, const float2* __restrict__ tx1,
                        const float2* __restrict__ tx2a,
                        const float* __restrict__ Wxz, const float* __restrict__ Wxh,
                        const float* __restrict__ bxz, const float* __restrict__ bhz,
                        const float* __restrict__ bxh, const float* __restrict__ bhh,
                        float* __restrict__ out, int n)
{
    int i = blockIdx.x * blockDim.x + threadIdx.x;
    if (i >= n) return;
    float2 t0 = x[i];
    float2 t1 = tx1[i];
    float2 ta = tx2a[i];
    float t2x = 2.0f * ta.x - t0.x;
    float t2y = 2.0f * ta.y - t0.y;
    float z = t0.x * Wxz[0] + t0.y * Wxz[1]
            + t1.x * Wxz[2] + t1.y * Wxz[3]
            + t2x  * Wxz[4] + t2y  * Wxz[5] + bxz[0] + bhz[0];
    float h = t0.x * Wxh[0] + t0.y * Wxh[1]
            + t1.x * Wxh[2] + t1.y * Wxh[3]
            + t2x  * Wxh[4] + t2y  * Wxh[5] + bxh[0] + bhh[0];
    float zs = 1.0f / (1.0f + expf(-z));
    float ht = tanhf(h);
    out[i] = (1.0f - zs) * ht;
}

// ---------------- launch ----------------

struct Lay {
    uint2* recD;
    unsigned* recS;
    float* dinv;
    float2 *y0, *y1, *tx1;
    float* part;               // split partials (deg: float, prop: float2)
    int *histS, *histD, *baseS, *baseD, *curS, *curD;
    size_t need;
};

static Lay make_layout(char* ws, long long ne, int n, int NBC, bool two_rec, int split)
{
    Lay L{};
    size_t off = 0;
    auto alloc = [&](size_t bytes) -> char* {
        char* p = ws + off;
        off = (off + bytes + 255) & ~(size_t)255;
        return p;
    };
    L.recD = (uint2*)alloc((size_t)ne * sizeof(uint2));
    L.recS = two_rec ? (unsigned*)alloc((size_t)ne * sizeof(unsigned))
                     : (unsigned*)L.recD;     // one_rec: recS lives in recD space
    L.dinv = (float*)alloc((size_t)n * sizeof(float));
    L.y0   = (float2*)alloc((size_t)n * sizeof(float2));
    L.y1   = (float2*)alloc((size_t)n * sizeof(float2));
    L.tx1  = (float2*)alloc((size_t)n * sizeof(float2));
    L.part = (float*)alloc((size_t)NBC * split * BSIZE * sizeof(float2));
    L.histS = (int*)alloc(NBC_MAX * sizeof(int));
    L.histD = (int*)alloc(NBC_MAX * sizeof(int));
    L.baseS = (int*)alloc(NBC_MAX * sizeof(int));
    L.baseD = (int*)alloc(NBC_MAX * sizeof(int));
    L.curS  = (int*)alloc(NBC_MAX * sizeof(int));
    L.curD  = (int*)alloc(NBC_MAX * sizeof(int));
    L.need = off;
    return L;
}

extern "C" void kernel_launch(void* const* d_in, const int* in_sizes, int n_in,
                              void* d_out, int out_size, void* d_ws, size_t ws_size,
                              hipStream_t stream)
{
    const float* x   = (const float*)d_in[0];
    const int*   ei  = (const int*)d_in[1];
    const float* w   = (const float*)d_in[2];
    const float* Wxz = (const float*)d_in[3];
    const float* Wxh = (const float*)d_in[5];
    const float* bxz = (const float*)d_in[9];
    const float* bhz = (const float*)d_in[10];
    const float* bxh = (const float*)d_in[13];
    const float* bhh = (const float*)d_in[14];

    const int n = in_sizes[0] / 2;
    const long long ne = in_sizes[2];
    const int* srcp = ei;
    const int* dstp = ei + ne;
    const int nblocks = (n + BLK - 1) / BLK;
    const int NBC = (n + BSIZE - 1) >> BSHIFT;
    const int NCH = (int)((ne + SCH - 1) / SCH);
    char* ws = (char*)d_ws;

    const bool nodes_ok = (n <= (1 << 19)) && (NBC <= NBC_MAX);

    // config preference: (two_rec, split8) > (two_rec,4) > (two_rec,1) >
    // (one_rec,4) > atomic fallback
    bool two_rec = true;
    int split = 8;
    Lay L = make_layout(ws, ne, n, NBC, true, 8);
    bool ok = nodes_ok && L.need <= ws_size;
    if (nodes_ok && !ok) {
        L = make_layout(ws, ne, n, NBC, true, 4); split = 4;
        ok = L.need <= ws_size;
    }
    if (nodes_ok && !ok) {
        L = make_layout(ws, ne, n, NBC, true, 1); split = 1;
        ok = L.need <= ws_size;
    }
    if (nodes_ok && !ok) {
        L = make_layout(ws, ne, n, NBC, false, 4); two_rec = false; split = 4;
        ok = L.need <= ws_size;
    }

    if (ok) {
        k_zero_ints<<<(2 * NBC_MAX + BLK - 1) / BLK, BLK, 0, stream>>>(L.histS, 2 * NBC_MAX);
        k_hist<<<2048, BLK, 0, stream>>>(srcp, dstp, L.histS, L.histD, ne, NBC);
        k_scan<<<2, BLK, 0, stream>>>(L.histS, L.baseS, L.curS, L.histD, L.baseD, L.curD, NBC);
        if (two_rec) {
            k_sortscatter<3><<<NCH, BLK_SS, 0, stream>>>(srcp, dstp, w, L.curS, L.curD,
                                                         L.recS, L.recD, ne, NBC, NCH);
            k_degacc<<<NBC * split, BLK_ACC, 0, stream>>>(L.recS, L.baseS, L.histS,
                                                          L.part, split);
            k_degfin<<<nblocks, BLK, 0, stream>>>(L.part, (const float2*)x,
                                                  L.dinv, L.y0, n, split);
        } else {
            // one_rec: 4B src records in recD's space, consumed before recD write
            k_sortscatter<1><<<NCH, BLK_SS, 0, stream>>>(srcp, dstp, w, L.curS, L.curD,
                                                         L.recS, L.recD, ne, NBC, NCH);
            k_degacc<<<NBC * split, BLK_ACC, 0, stream>>>(L.recS, L.baseS, L.histS,
                                                          L.part, split);
            k_degfin<<<nblocks, BLK, 0, stream>>>(L.part, (const float2*)x,
                                                  L.dinv, L.y0, n, split);
            k_sortscatter<2><<<NCH, BLK_SS, 0, stream>>>(srcp, dstp, w, L.curS, L.curD,
                                                         L.recS, L.recD, ne, NBC, NCH);
        }
        k_propacc<<<NBC * split, BLK_ACC, 0, stream>>>(L.recD, L.baseD, L.histD,
                                                       L.y0, (float2*)L.part, split);
        k_propfin1<<<nblocks, BLK, 0, stream>>>((const float2*)L.part, L.dinv,
                                                L.tx1, L.y1, n, split);
        k_propacc<<<NBC * split, BLK_ACC, 0, stream>>>(L.recD, L.baseD, L.histD,
                                                       L.y1, (float2*)L.part, split);
        k_propfin2<<<nblocks, BLK, 0, stream>>>((const float2*)L.part, L.dinv,
                                                (const float2*)x, L.tx1,
                                                Wxz, Wxh, bxz, bhz, bxh, bhh,
                                                (float*)d_out, n, split);
    } else {
        // last-resort: global-atomic path
        size_t foff = 0;
        auto falloc = [&](size_t bytes) -> char* {
            char* p = ws + foff;
            foff = (foff + bytes + 255) & ~(size_t)255;
            return p;
        };
        float* deg   = (float*)falloc((size_t)n * sizeof(float));
        float* ftx1  = (float*)falloc((size_t)n * 2 * sizeof(float));
        float* ftx2a = (float*)falloc((size_t)n * 2 * sizeof(float));
        const long long n4 = (long long)(foff / 16);
        k_zero_f4<<<1024, BLK, 0, stream>>>((float4*)ws, n4);
        k_deg_atomic<<<4096, BLK, 0, stream>>>(srcp, dstp, w, deg, ne);
        k_dinv_inplace<<<nblocks, BLK, 0, stream>>>(deg, n);
        k_prop_atomic<<<4096, BLK, 0, stream>>>(srcp, dstp, w, deg,
                                                (const float2*)x, ftx1, ne);
        k_prop_atomic<<<4096, BLK, 0, stream>>>(srcp, dstp, w, deg,
                                                (const float2*)ftx1, ftx2a, ne);
        k_final<<<nblocks, BLK, 0, stream>>>((const float2*)x, (const float2*)ftx1,
                                             (const float2*)ftx2a,
                                             Wxz, Wxh, bxz, bhz, bxh, bhh,
                                             (float*)d_out, n);
    }
}